// Round 1
// baseline (920.153 us; speedup 1.0000x reference)
//
#include <hip/hip_runtime.h>
#include <cstdint>

#define NB 8
#define NC 96
#define NC2 192
#define NPT 3136    // 56*56
#define NK 9
#define NT 128      // knn j-tile width
static constexpr float BN_EPS = 1e-5f;

// ---------------- K1: fold BN into weights, build fused weight layouts ----------------
__global__ void k_fuse(const float* __restrict__ W1, const float* __restrict__ b1,
                       const float* __restrict__ g1, const float* __restrict__ be1,
                       const float* __restrict__ m1, const float* __restrict__ v1,
                       const float* __restrict__ Wg,
                       const float* __restrict__ W2, const float* __restrict__ b2,
                       const float* __restrict__ g2, const float* __restrict__ be2,
                       const float* __restrict__ m2, const float* __restrict__ v2,
                       float* __restrict__ W1f, float* __restrict__ b1f,
                       float* __restrict__ Wuv,
                       float* __restrict__ W2f, float* __restrict__ b2f) {
  int t = blockIdx.x * blockDim.x + threadIdx.x;
  int nth = gridDim.x * blockDim.x;
  // W1f[c][o] = W1[o][c] * inv1[o]
  for (int i = t; i < NC * NC; i += nth) {
    int c = i / NC, o = i % NC;
    float inv = g1[o] / sqrtf(v1[o] + BN_EPS);
    W1f[i] = W1[o * NC + c] * inv;
  }
  for (int o = t; o < NC; o += nth) {
    float inv = g1[o] / sqrtf(v1[o] + BN_EPS);
    b1f[o] = b1[o] * inv + be1[o] - m1[o] * inv;
    float inv2v = g2[o] / sqrtf(v2[o] + BN_EPS);
    b2f[o] = b2[o] * inv2v + be2[o] - m2[o] * inv2v;
  }
  // Wuv[c][o4], o4<192: A = Wg[o][c] - Wg[o][c+96]; o4>=192: B = Wg[o][c+96]
  for (int i = t; i < NC * (2 * NC2); i += nth) {
    int c = i / (2 * NC2), o4 = i % (2 * NC2);
    float val;
    if (o4 < NC2) val = Wg[o4 * NC2 + c] - Wg[o4 * NC2 + NC + c];
    else          val = Wg[(o4 - NC2) * NC2 + NC + c];
    Wuv[i] = val;
  }
  // W2f[c][o] = W2[o][c] * inv2[o]   (c in [0,192), o in [0,96))
  for (int i = t; i < NC2 * NC; i += nth) {
    int c = i / NC, o = i % NC;
    float inv = g2[o] / sqrtf(v2[o] + BN_EPS);
    W2f[i] = W2[o * NC2 + c] * inv;
  }
}

// ---------------- K2: feat = BN(W1 x + b1); fn = feat/||feat||; sqv = sum fn^2 ----------
__global__ __launch_bounds__(256) void k_feat(const float* __restrict__ x,
                                              const float* __restrict__ W1f,
                                              const float* __restrict__ b1f,
                                              float* __restrict__ feat,
                                              float* __restrict__ fn,
                                              float* __restrict__ sqv) {
  __shared__ float w_lds[NC * NC];
  int b = blockIdx.y;
  int n = blockIdx.x * 256 + threadIdx.x;
  for (int i = threadIdx.x * 4; i < NC * NC; i += 1024)
    *(float4*)&w_lds[i] = *(const float4*)&W1f[i];
  __syncthreads();
  if (n < NPT) {
    const float* xb = x + (size_t)b * NC * NPT;
    float acc[NC];
#pragma unroll
    for (int o = 0; o < NC; ++o) acc[o] = b1f[o];
    for (int c = 0; c < NC; ++c) {
      float xv = xb[c * NPT + n];
#pragma unroll
      for (int o4 = 0; o4 < NC / 4; ++o4) {
        float4 wv = *(float4*)&w_lds[c * NC + o4 * 4];
        acc[o4 * 4 + 0] = fmaf(wv.x, xv, acc[o4 * 4 + 0]);
        acc[o4 * 4 + 1] = fmaf(wv.y, xv, acc[o4 * 4 + 1]);
        acc[o4 * 4 + 2] = fmaf(wv.z, xv, acc[o4 * 4 + 2]);
        acc[o4 * 4 + 3] = fmaf(wv.w, xv, acc[o4 * 4 + 3]);
      }
    }
    float sq = 0.f;
#pragma unroll
    for (int o = 0; o < NC; ++o) sq += acc[o] * acc[o];
    float den = fmaxf(sqrtf(sq), 1e-12f);
    float sqn = 0.f;
    float* fb = feat + (size_t)b * NC * NPT + n;
    float* fnb = fn + (size_t)b * NC * NPT + n;
#pragma unroll
    for (int o = 0; o < NC; ++o) {
      float f = acc[o];
      fb[(size_t)o * NPT] = f;
      float v = f / den;
      fnb[(size_t)o * NPT] = v;
      sqn += v * v;
    }
    sqv[b * NPT + n] = sqn;
  }
}

// ---------------- K3: exact KNN (top-9 smallest dist, tie -> lower index) --------------
// block = 256 thr = 4 waves; wave owns 8 rows; lane owns 2 j-columns per tile (NT=128).
__global__ __launch_bounds__(256) void k_knn(const float* __restrict__ fn,
                                             const float* __restrict__ sqv,
                                             int* __restrict__ nn_idx) {
  int fid = blockIdx.x;
  int b = fid & 7;          // XCD affinity: per-batch fn stays in one XCD's L2
  int rb = fid >> 3;        // 98 row-blocks of 32 rows
  int w = threadIdx.x >> 6, lane = threadIdx.x & 63;
  int i0 = rb * 32;

  __shared__ float rows[4 * NC * 8];          // [wave][c][r]
  __shared__ float accs[4 * 8 * (NT + 2)];    // [wave][r][j] padded
  __shared__ float md[4 * 8 * 8 * NK];
  __shared__ int   mi[4 * 8 * 8 * NK];

  const float* fnb = fn + (size_t)b * NC * NPT;
  const float* sqb = sqv + b * NPT;

  {  // stage the 32 row vectors
    int r = threadIdx.x & 31, c0 = threadIdx.x >> 5;
    for (int c = c0; c < NC; c += 8)
      rows[((r >> 3) * NC + c) * 8 + (r & 7)] = fnb[(size_t)c * NPT + i0 + r];
  }
  __syncthreads();

  int rsel = lane >> 3, q = lane & 7;
  float sqi = sqb[i0 + w * 8 + rsel];
  float d9[NK]; int i9[NK];
#pragma unroll
  for (int t = 0; t < NK; ++t) { d9[t] = 1e30f; i9[t] = 0x7fffffff; }

  const float* rw = &rows[w * NC * 8];
  float* aw = &accs[w * 8 * (NT + 2)];
  const int NTILES = (NPT + NT - 1) / NT;  // 25

  for (int tile = 0; tile < NTILES; ++tile) {
    int j0 = tile * NT;
    int jA = j0 + 2 * lane;
    int jc = min(jA, NPT - 2);  // clamp; OOB j discarded at insert
    float2 a[8];
#pragma unroll
    for (int r = 0; r < 8; ++r) a[r] = make_float2(0.f, 0.f);
    for (int c = 0; c < NC; ++c) {
      float2 xv = *(const float2*)&fnb[(size_t)c * NPT + jc];
      float4 r03 = *(const float4*)&rw[c * 8];
      float4 r47 = *(const float4*)&rw[c * 8 + 4];
      float rv[8] = {r03.x, r03.y, r03.z, r03.w, r47.x, r47.y, r47.z, r47.w};
#pragma unroll
      for (int r = 0; r < 8; ++r) {
        a[r].x = fmaf(rv[r], xv.x, a[r].x);
        a[r].y = fmaf(rv[r], xv.y, a[r].y);
      }
    }
    __syncthreads();  // previous tile's accs fully consumed
#pragma unroll
    for (int r = 0; r < 8; ++r)
      *(float2*)&aw[r * (NT + 2) + 2 * lane] = a[r];
    __syncthreads();
#pragma unroll
    for (int t = 0; t < 16; ++t) {
      int jj = q * 16 + t;
      int j = j0 + jj;
      if (j < NPT) {
        float dot = aw[rsel * (NT + 2) + jj];
        float d = (sqi + sqb[j]) - 2.0f * dot;
        if (d < d9[8] || (d == d9[8] && j < i9[8])) {
          d9[8] = d; i9[8] = j;
#pragma unroll
          for (int s = 8; s > 0; --s) {
            bool sw = (d9[s] < d9[s - 1]) || (d9[s] == d9[s - 1] && i9[s] < i9[s - 1]);
            float td = d9[s - 1]; int ti = i9[s - 1];
            d9[s - 1] = sw ? d9[s] : td;
            i9[s - 1] = sw ? i9[s] : ti;
            d9[s] = sw ? td : d9[s];
            i9[s] = sw ? ti : i9[s];
          }
        }
      }
    }
  }

  // merge 8 sorted lists per row
#pragma unroll
  for (int t = 0; t < NK; ++t) {
    md[((w * 8 + rsel) * 8 + q) * NK + t] = d9[t];
    mi[((w * 8 + rsel) * 8 + q) * NK + t] = i9[t];
  }
  __syncthreads();
  if (lane < 8) {
    int r = lane;
    int irow = i0 + w * 8 + r;
    int ptr[8];
#pragma unroll
    for (int qq = 0; qq < 8; ++qq) ptr[qq] = 0;
    int* outp = nn_idx + ((size_t)b * NPT + irow) * NK;
    for (int kk = 0; kk < NK; ++kk) {
      float bd = 1e30f; int bi = 0x7fffffff; int bq = 0;
#pragma unroll
      for (int qq = 0; qq < 8; ++qq) {
        int p = ptr[qq];
        float dq = (p < NK) ? md[((w * 8 + r) * 8 + qq) * NK + p] : 1e30f;
        int iq = (p < NK) ? mi[((w * 8 + r) * 8 + qq) * NK + p] : 0x7fffffff;
        bool better = (dq < bd) || (dq == bd && iq < bi);
        bd = better ? dq : bd; bi = better ? iq : bi; bq = better ? qq : bq;
      }
      outp[kk] = bi;
#pragma unroll
      for (int qq = 0; qq < 8; ++qq) if (qq == bq) ptr[qq]++;
    }
  }
}

// ---------------- K4: uvt[b][n][0:192]=A@feat+bg, [192:384]=Bm@feat (transposed store) --
__global__ __launch_bounds__(256) void k_uv(const float* __restrict__ feat,
                                            const float* __restrict__ Wuv,
                                            const float* __restrict__ bg,
                                            float* __restrict__ uvt) {
  __shared__ float w_lds[24 * 384];
  int b = blockIdx.y;
  int n0 = blockIdx.x * 64;
  int lane = threadIdx.x & 63, og = threadIdx.x >> 6;
  int n = n0 + lane;
  const float* fb = feat + (size_t)b * NC * NPT;
  float acc[96];
#pragma unroll
  for (int oo = 0; oo < 96; ++oo) acc[oo] = 0.f;
  for (int ch = 0; ch < 4; ++ch) {
    __syncthreads();
    for (int i = threadIdx.x * 4; i < 24 * 384; i += 1024)
      *(float4*)&w_lds[i] = *(const float4*)&Wuv[ch * 24 * 384 + i];
    __syncthreads();
    for (int cc = 0; cc < 24; ++cc) {
      int c = ch * 24 + cc;
      float xv = fb[(size_t)c * NPT + n];
#pragma unroll
      for (int o4 = 0; o4 < 24; ++o4) {
        float4 wv = *(float4*)&w_lds[cc * 384 + og * 96 + o4 * 4];
        acc[o4 * 4 + 0] = fmaf(wv.x, xv, acc[o4 * 4 + 0]);
        acc[o4 * 4 + 1] = fmaf(wv.y, xv, acc[o4 * 4 + 1]);
        acc[o4 * 4 + 2] = fmaf(wv.z, xv, acc[o4 * 4 + 2]);
        acc[o4 * 4 + 3] = fmaf(wv.w, xv, acc[o4 * 4 + 3]);
      }
    }
  }
  float* up = uvt + ((size_t)b * NPT + n) * 384 + og * 96;
#pragma unroll
  for (int o4 = 0; o4 < 24; ++o4) {
    float4 v;
    v.x = acc[o4 * 4 + 0]; v.y = acc[o4 * 4 + 1];
    v.z = acc[o4 * 4 + 2]; v.w = acc[o4 * 4 + 3];
    if (og < 2) {
      int ob = og * 96 + o4 * 4;
      v.x += bg[ob + 0]; v.y += bg[ob + 1]; v.z += bg[ob + 2]; v.w += bg[ob + 3];
    }
    *(float4*)&up[o4 * 4] = v;
  }
}

// ---------------- K5: agg_t[n][o] = relu(max_k (u[n][o] + v[idx[n][k]][o])) ------------
__global__ __launch_bounds__(192) void k_gather(const float* __restrict__ uvt,
                                                const int* __restrict__ nn_idx,
                                                float* __restrict__ aggt) {
  int fid = blockIdx.x;
  int b = fid & 7;      // XCD affinity for the per-batch v table (2.4 MB < 4 MB L2)
  int n = fid >> 3;
  int o = threadIdx.x;
  const float* base = uvt + (size_t)b * NPT * 384;
  const int* ip = nn_idx + ((size_t)b * NPT + n) * NK;
  float u = base[(size_t)n * 384 + o];
  float acc = -1e30f;
#pragma unroll
  for (int k = 0; k < NK; ++k) {
    int j = ip[k];
    float v = base[(size_t)j * 384 + 192 + o];
    acc = fmaxf(acc, u + v);
  }
  aggt[((size_t)b * NPT + n) * 192 + o] = fmaxf(acc, 0.f);
}

// ---------------- K6: out = W2f @ agg + b2f + residual ---------------------------------
__global__ __launch_bounds__(256) void k_out(const float* __restrict__ aggt,
                                             const float* __restrict__ W2f,
                                             const float* __restrict__ b2f,
                                             const float* __restrict__ x,
                                             float* __restrict__ out) {
  __shared__ float w_lds[96 * 96];
  __shared__ float a_lds[64 * 97];
  int b = blockIdx.y;
  int n0 = blockIdx.x * 64;
  int lane = threadIdx.x & 63, og = threadIdx.x >> 6;
  int n = n0 + lane;
  float acc[24];
#pragma unroll
  for (int oo = 0; oo < 24; ++oo) acc[oo] = 0.f;
  const float* ab = aggt + ((size_t)b * NPT + n0) * 192;
  for (int ch = 0; ch < 2; ++ch) {
    __syncthreads();
    for (int i = threadIdx.x * 4; i < 96 * 96; i += 1024)
      *(float4*)&w_lds[i] = *(const float4*)&W2f[ch * 96 * 96 + i];
    for (int fidx = threadIdx.x; fidx < 64 * 24; fidx += 256) {
      int r = fidx / 24, cc4 = fidx % 24;
      float4 v = *(const float4*)&ab[(size_t)r * 192 + ch * 96 + cc4 * 4];
      a_lds[r * 97 + cc4 * 4 + 0] = v.x;
      a_lds[r * 97 + cc4 * 4 + 1] = v.y;
      a_lds[r * 97 + cc4 * 4 + 2] = v.z;
      a_lds[r * 97 + cc4 * 4 + 3] = v.w;
    }
    __syncthreads();
    for (int cc = 0; cc < 96; ++cc) {
      float a = a_lds[lane * 97 + cc];
#pragma unroll
      for (int o4 = 0; o4 < 6; ++o4) {
        float4 wv = *(float4*)&w_lds[cc * 96 + og * 24 + o4 * 4];
        acc[o4 * 4 + 0] = fmaf(wv.x, a, acc[o4 * 4 + 0]);
        acc[o4 * 4 + 1] = fmaf(wv.y, a, acc[o4 * 4 + 1]);
        acc[o4 * 4 + 2] = fmaf(wv.z, a, acc[o4 * 4 + 2]);
        acc[o4 * 4 + 3] = fmaf(wv.w, a, acc[o4 * 4 + 3]);
      }
    }
  }
  const float* xb = x + (size_t)b * NC * NPT;
  float* ob = out + (size_t)b * NC * NPT;
#pragma unroll
  for (int oo = 0; oo < 24; ++oo) {
    int o = og * 24 + oo;
    ob[(size_t)o * NPT + n] = acc[oo] + b2f[o] + xb[(size_t)o * NPT + n];
  }
}

extern "C" void kernel_launch(void* const* d_in, const int* in_sizes, int n_in,
                              void* d_out, int out_size, void* d_ws, size_t ws_size,
                              hipStream_t stream) {
  const float* x  = (const float*)d_in[0];
  const float* W1 = (const float*)d_in[1];
  const float* b1 = (const float*)d_in[2];
  const float* g1 = (const float*)d_in[3];
  const float* be1= (const float*)d_in[4];
  const float* m1 = (const float*)d_in[5];
  const float* v1 = (const float*)d_in[6];
  const float* Wg = (const float*)d_in[7];
  const float* bg = (const float*)d_in[8];
  const float* W2 = (const float*)d_in[9];
  const float* b2 = (const float*)d_in[10];
  const float* g2 = (const float*)d_in[11];
  const float* be2= (const float*)d_in[12];
  const float* m2 = (const float*)d_in[13];
  const float* v2 = (const float*)d_in[14];
  float* out = (float*)d_out;

  float* ws = (float*)d_ws;
  size_t off = 0;
  float* feat = ws + off; off += (size_t)NB * NC * NPT;     // 2408448
  float* fnp  = ws + off; off += (size_t)NB * NC * NPT;     // 2408448
  float* sqv  = ws + off; off += (size_t)NB * NPT;          // 25088
  float* uvt  = ws + off; off += (size_t)NB * NPT * 384;    // 9633792
  float* aggt = ws + off; off += (size_t)NB * NPT * 192;    // 4816896
  float* W1f  = ws + off; off += NC * NC;                   // 9216
  float* Wuv  = ws + off; off += NC * 2 * NC2;              // 36864
  float* W2f  = ws + off; off += NC2 * NC;                  // 18432
  float* b1f  = ws + off; off += 128;
  float* b2f  = ws + off; off += 128;
  int* nn_idx = (int*)(ws + off); off += (size_t)NB * NPT * NK;

  k_fuse<<<dim3(64), 256, 0, stream>>>(W1, b1, g1, be1, m1, v1, Wg, W2, b2, g2, be2, m2, v2,
                                       W1f, b1f, Wuv, W2f, b2f);
  k_feat<<<dim3((NPT + 255) / 256, NB), 256, 0, stream>>>(x, W1f, b1f, feat, fnp, sqv);
  k_knn<<<dim3(NB * (NPT / 32)), 256, 0, stream>>>(fnp, sqv, nn_idx);
  k_uv<<<dim3(NPT / 64, NB), 256, 0, stream>>>(feat, Wuv, bg, uvt);
  k_gather<<<dim3(NB * NPT), 192, 0, stream>>>(uvt, nn_idx, aggt);
  k_out<<<dim3(NPT / 64, NB), 256, 0, stream>>>(aggt, W2f, b2f, x, out);
}

// Round 2
// 749.829 us; speedup vs baseline: 1.2272x; 1.2272x over previous
//
#include <hip/hip_runtime.h>
#include <cstdint>

#define NB 8
#define NC 96
#define NC2 192
#define NPT 3136    // 56*56
#define NK 9
#define NT 128      // knn j-tile width
#define JHALF 1568  // NPT/2
#define NTILES_H 13 // ceil(1568/128): 12 full + 1 partial(32)
static constexpr float BN_EPS = 1e-5f;
typedef unsigned long long u64;

// ---------------- K1: fold BN into weights, build fused weight layouts ----------------
__global__ void k_fuse(const float* __restrict__ W1, const float* __restrict__ b1,
                       const float* __restrict__ g1, const float* __restrict__ be1,
                       const float* __restrict__ m1, const float* __restrict__ v1,
                       const float* __restrict__ Wg,
                       const float* __restrict__ W2, const float* __restrict__ b2,
                       const float* __restrict__ g2, const float* __restrict__ be2,
                       const float* __restrict__ m2, const float* __restrict__ v2,
                       float* __restrict__ W1f, float* __restrict__ b1f,
                       float* __restrict__ Wuv,
                       float* __restrict__ W2f, float* __restrict__ b2f) {
  int t = blockIdx.x * blockDim.x + threadIdx.x;
  int nth = gridDim.x * blockDim.x;
  for (int i = t; i < NC * NC; i += nth) {
    int c = i / NC, o = i % NC;
    float inv = g1[o] / sqrtf(v1[o] + BN_EPS);
    W1f[i] = W1[o * NC + c] * inv;
  }
  for (int o = t; o < NC; o += nth) {
    float inv = g1[o] / sqrtf(v1[o] + BN_EPS);
    b1f[o] = b1[o] * inv + be1[o] - m1[o] * inv;
    float inv2v = g2[o] / sqrtf(v2[o] + BN_EPS);
    b2f[o] = b2[o] * inv2v + be2[o] - m2[o] * inv2v;
  }
  for (int i = t; i < NC * (2 * NC2); i += nth) {
    int c = i / (2 * NC2), o4 = i % (2 * NC2);
    float val;
    if (o4 < NC2) val = Wg[o4 * NC2 + c] - Wg[o4 * NC2 + NC + c];
    else          val = Wg[(o4 - NC2) * NC2 + NC + c];
    Wuv[i] = val;
  }
  for (int i = t; i < NC2 * NC; i += nth) {
    int c = i / NC, o = i % NC;
    float inv = g2[o] / sqrtf(v2[o] + BN_EPS);
    W2f[i] = W2[o * NC2 + c] * inv;
  }
}

// ---------------- K2: feat = BN(W1 x + b1); fn = feat/||feat||; sqv = sum fn^2 ----------
__global__ __launch_bounds__(256) void k_feat(const float* __restrict__ x,
                                              const float* __restrict__ W1f,
                                              const float* __restrict__ b1f,
                                              float* __restrict__ feat,
                                              float* __restrict__ fn,
                                              float* __restrict__ sqv) {
  __shared__ float w_lds[NC * NC];
  int b = blockIdx.y;
  int n = blockIdx.x * 256 + threadIdx.x;
  for (int i = threadIdx.x * 4; i < NC * NC; i += 1024)
    *(float4*)&w_lds[i] = *(const float4*)&W1f[i];
  __syncthreads();
  if (n < NPT) {
    const float* xb = x + (size_t)b * NC * NPT;
    float acc[NC];
#pragma unroll
    for (int o = 0; o < NC; ++o) acc[o] = b1f[o];
    for (int c = 0; c < NC; ++c) {
      float xv = xb[c * NPT + n];
#pragma unroll
      for (int o4 = 0; o4 < NC / 4; ++o4) {
        float4 wv = *(float4*)&w_lds[c * NC + o4 * 4];
        acc[o4 * 4 + 0] = fmaf(wv.x, xv, acc[o4 * 4 + 0]);
        acc[o4 * 4 + 1] = fmaf(wv.y, xv, acc[o4 * 4 + 1]);
        acc[o4 * 4 + 2] = fmaf(wv.z, xv, acc[o4 * 4 + 2]);
        acc[o4 * 4 + 3] = fmaf(wv.w, xv, acc[o4 * 4 + 3]);
      }
    }
    float sq = 0.f;
#pragma unroll
    for (int o = 0; o < NC; ++o) sq += acc[o] * acc[o];
    float den = fmaxf(sqrtf(sq), 1e-12f);
    float sqn = 0.f;
    float* fb = feat + (size_t)b * NC * NPT + n;
    float* fnb = fn + (size_t)b * NC * NPT + n;
#pragma unroll
    for (int o = 0; o < NC; ++o) {
      float f = acc[o];
      fb[(size_t)o * NPT] = f;
      float v = f / den;
      fnb[(size_t)o * NPT] = v;
      sqn += v * v;
    }
    sqv[b * NPT + n] = sqn;
  }
}

// ---------------- K3: exact KNN, half-j per block, u64 (dist|idx) keys -----------------
// block = 256 thr = 4 waves; wave owns 8 rows; lane owns 2 j-columns per tile (NT=128).
// Each block scans one j-half (1568 cols) for its 32 rows; writes sorted 9-key list
// per (row, half) to pk; k_nnmerge merges the two halves.
__global__ __launch_bounds__(256) void k_knn(const float* __restrict__ fn,
                                             const float* __restrict__ sqv,
                                             u64* __restrict__ pk) {
  int fid = blockIdx.x;
  int b = fid & 7;            // XCD affinity: per-batch fn stays in one XCD's L2
  int rh = fid >> 3;          // 196 = 98 row-blocks x 2 halves
  int rb = rh >> 1;
  int half = rh & 1;
  int w = threadIdx.x >> 6, lane = threadIdx.x & 63;
  int i0 = rb * 32;
  int jbase = half * JHALF;
  int jend = jbase + JHALF;

  __shared__ float rows[4 * NC * 8];                   // [wave][c][r]  12288 B
  __shared__ __align__(16) unsigned char upool[18432]; // accs (17408) / keys (18432) union
  unsigned* awu_all = (unsigned*)upool;                // [4][8][136]
  u64* keys = (u64*)upool;                             // [4*8][8][9]

  const float* fnb = fn + (size_t)b * NC * NPT;
  const float* sqb = sqv + b * NPT;

  {  // stage the 32 row vectors
    int r = threadIdx.x & 31, c0 = threadIdx.x >> 5;
    for (int c = c0; c < NC; c += 8)
      rows[((r >> 3) * NC + c) * 8 + (r & 7)] = fnb[(size_t)c * NPT + i0 + r];
  }
  __syncthreads();

  int rsel = lane >> 3, q = lane & 7;
  u64 k9[NK];
#pragma unroll
  for (int t = 0; t < NK; ++t) k9[t] = ~0ull;

  const float* rw = &rows[w * NC * 8];
  unsigned* aw = awu_all + w * 8 * 136;
  const unsigned* awr = aw + rsel * 136;

  for (int tile = 0; tile < NTILES_H; ++tile) {
    int j0 = jbase + tile * NT;
    int jA = j0 + 2 * lane;
    bool valid = jA < jend;
    int jc = min(jA, NPT - 2);
    float2 a[8];
#pragma unroll
    for (int r = 0; r < 8; ++r) a[r] = make_float2(0.f, 0.f);
#pragma unroll 8
    for (int c = 0; c < NC; ++c) {
      float2 xv = *(const float2*)&fnb[(size_t)c * NPT + jc];
      float4 r03 = *(const float4*)&rw[c * 8];
      float4 r47 = *(const float4*)&rw[c * 8 + 4];
      float rv[8] = {r03.x, r03.y, r03.z, r03.w, r47.x, r47.y, r47.z, r47.w};
#pragma unroll
      for (int r = 0; r < 8; ++r) {
        a[r].x = fmaf(rv[r], xv.x, a[r].x);
        a[r].y = fmaf(rv[r], xv.y, a[r].y);
      }
    }
    float2 sq2 = *(const float2*)&sqb[jc];
    __syncthreads();  // previous tile's awu fully consumed
#pragma unroll
    for (int r = 0; r < 8; ++r) {
      // d_rel = sqb[j] - 2*dot  (order-equivalent to ref dist within a row)
      float dx = fmaf(-2.f, a[r].x, sq2.x);
      float dy = fmaf(-2.f, a[r].y, sq2.y);
      unsigned ux = __float_as_uint(dx);
      unsigned uy = __float_as_uint(dy);
      ux ^= 0x80000000u | (unsigned)((int)ux >> 31);  // monotone map f32 -> u32
      uy ^= 0x80000000u | (unsigned)((int)uy >> 31);
      uint2 st;
      st.x = valid ? ux : 0xFFFFFFFFu;
      st.y = valid ? uy : 0xFFFFFFFFu;
      *(uint2*)&aw[r * 136 + 2 * lane] = st;
    }
    __syncthreads();
#pragma unroll 4
    for (int t16 = 0; t16 < 16; ++t16) {
      int jj = t16 * 8 + q;
      unsigned hi = awr[jj];
      u64 key = ((u64)hi << 32) | (unsigned)(j0 + jj);
      if (key < k9[8]) {
        k9[8] = key;
#pragma unroll
        for (int s = 8; s > 0; --s) {
          u64 x = k9[s - 1], y = k9[s];
          bool sw = y < x;
          k9[s - 1] = sw ? y : x;
          k9[s] = sw ? x : y;
        }
      }
    }
  }

  __syncthreads();  // repurpose upool as merge key store
#pragma unroll
  for (int t = 0; t < NK; ++t)
    keys[((w * 8 + rsel) * 8 + q) * NK + t] = k9[t];
  __syncthreads();
  if (lane < 8) {
    int r = lane;
    const u64* kl = &keys[(w * 8 + r) * 8 * NK];
    int ptr[8];
#pragma unroll
    for (int qq = 0; qq < 8; ++qq) ptr[qq] = 0;
    u64* outp = pk + ((size_t)(b * NPT + i0 + w * 8 + r) * 2 + half) * NK;
    for (int kk = 0; kk < NK; ++kk) {
      u64 best = ~0ull; int bq = 0;
#pragma unroll
      for (int qq = 0; qq < 8; ++qq) {
        int p = ptr[qq];
        u64 kq = (p < NK) ? kl[qq * NK + p] : ~0ull;
        if (kq < best) { best = kq; bq = qq; }
      }
      outp[kk] = best;
#pragma unroll
      for (int qq = 0; qq < 8; ++qq) if (qq == bq) ptr[qq]++;
    }
  }
}

// ---------------- K3b: merge the two sorted half-lists per row -------------------------
__global__ __launch_bounds__(256) void k_nnmerge(const u64* __restrict__ pk,
                                                 int* __restrict__ nn_idx) {
  int rg = blockIdx.x * 256 + threadIdx.x;
  if (rg >= NB * NPT) return;
  const u64* pa = pk + (size_t)rg * 2 * NK;
  const u64* pb = pa + NK;
  int na = 0, nb = 0;
  int* op = nn_idx + (size_t)rg * NK;
#pragma unroll
  for (int kk = 0; kk < NK; ++kk) {
    u64 ka = pa[na];
    u64 kb = pb[nb];
    bool ta = ka < kb;
    op[kk] = (int)(unsigned)(ta ? ka : kb);
    na += ta ? 1 : 0; nb += ta ? 0 : 1;
  }
}

// ---------------- K4: uvt[b][n][0:192]=A@feat+bg, [192:384]=Bm@feat (transposed store) --
__global__ __launch_bounds__(256) void k_uv(const float* __restrict__ feat,
                                            const float* __restrict__ Wuv,
                                            const float* __restrict__ bg,
                                            float* __restrict__ uvt) {
  __shared__ float w_lds[24 * 384];
  int b = blockIdx.y;
  int n0 = blockIdx.x * 64;
  int lane = threadIdx.x & 63, og = threadIdx.x >> 6;
  int n = n0 + lane;
  const float* fb = feat + (size_t)b * NC * NPT;
  float acc[96];
#pragma unroll
  for (int oo = 0; oo < 96; ++oo) acc[oo] = 0.f;
  for (int ch = 0; ch < 4; ++ch) {
    __syncthreads();
    for (int i = threadIdx.x * 4; i < 24 * 384; i += 1024)
      *(float4*)&w_lds[i] = *(const float4*)&Wuv[ch * 24 * 384 + i];
    __syncthreads();
    for (int cc = 0; cc < 24; ++cc) {
      int c = ch * 24 + cc;
      float xv = fb[(size_t)c * NPT + n];
#pragma unroll
      for (int o4 = 0; o4 < 24; ++o4) {
        float4 wv = *(float4*)&w_lds[cc * 384 + og * 96 + o4 * 4];
        acc[o4 * 4 + 0] = fmaf(wv.x, xv, acc[o4 * 4 + 0]);
        acc[o4 * 4 + 1] = fmaf(wv.y, xv, acc[o4 * 4 + 1]);
        acc[o4 * 4 + 2] = fmaf(wv.z, xv, acc[o4 * 4 + 2]);
        acc[o4 * 4 + 3] = fmaf(wv.w, xv, acc[o4 * 4 + 3]);
      }
    }
  }
  float* up = uvt + ((size_t)b * NPT + n) * 384 + og * 96;
#pragma unroll
  for (int o4 = 0; o4 < 24; ++o4) {
    float4 v;
    v.x = acc[o4 * 4 + 0]; v.y = acc[o4 * 4 + 1];
    v.z = acc[o4 * 4 + 2]; v.w = acc[o4 * 4 + 3];
    if (og < 2) {
      int ob = og * 96 + o4 * 4;
      v.x += bg[ob + 0]; v.y += bg[ob + 1]; v.z += bg[ob + 2]; v.w += bg[ob + 3];
    }
    *(float4*)&up[o4 * 4] = v;
  }
}

// ---------------- K5: agg_t[n][o] = relu(max_k (u[n][o] + v[idx[n][k]][o])) ------------
__global__ __launch_bounds__(192) void k_gather(const float* __restrict__ uvt,
                                                const int* __restrict__ nn_idx,
                                                float* __restrict__ aggt) {
  int fid = blockIdx.x;
  int b = fid & 7;      // XCD affinity for the per-batch v table
  int n = fid >> 3;
  int o = threadIdx.x;
  const float* base = uvt + (size_t)b * NPT * 384;
  const int* ip = nn_idx + ((size_t)b * NPT + n) * NK;
  float u = base[(size_t)n * 384 + o];
  float acc = -1e30f;
#pragma unroll
  for (int k = 0; k < NK; ++k) {
    int j = ip[k];
    float v = base[(size_t)j * 384 + 192 + o];
    acc = fmaxf(acc, u + v);
  }
  aggt[((size_t)b * NPT + n) * 192 + o] = fmaxf(acc, 0.f);
}

// ---------------- K6: out = W2f @ agg + b2f + residual ---------------------------------
__global__ __launch_bounds__(256) void k_out(const float* __restrict__ aggt,
                                             const float* __restrict__ W2f,
                                             const float* __restrict__ b2f,
                                             const float* __restrict__ x,
                                             float* __restrict__ out) {
  __shared__ float w_lds[96 * 96];
  __shared__ float a_lds[64 * 97];
  int b = blockIdx.y;
  int n0 = blockIdx.x * 64;
  int lane = threadIdx.x & 63, og = threadIdx.x >> 6;
  int n = n0 + lane;
  float acc[24];
#pragma unroll
  for (int oo = 0; oo < 24; ++oo) acc[oo] = 0.f;
  const float* ab = aggt + ((size_t)b * NPT + n0) * 192;
  for (int ch = 0; ch < 2; ++ch) {
    __syncthreads();
    for (int i = threadIdx.x * 4; i < 96 * 96; i += 1024)
      *(float4*)&w_lds[i] = *(const float4*)&W2f[ch * 96 * 96 + i];
    for (int fidx = threadIdx.x; fidx < 64 * 24; fidx += 256) {
      int r = fidx / 24, cc4 = fidx % 24;
      float4 v = *(const float4*)&ab[(size_t)r * 192 + ch * 96 + cc4 * 4];
      a_lds[r * 97 + cc4 * 4 + 0] = v.x;
      a_lds[r * 97 + cc4 * 4 + 1] = v.y;
      a_lds[r * 97 + cc4 * 4 + 2] = v.z;
      a_lds[r * 97 + cc4 * 4 + 3] = v.w;
    }
    __syncthreads();
    for (int cc = 0; cc < 96; ++cc) {
      float a = a_lds[lane * 97 + cc];
#pragma unroll
      for (int o4 = 0; o4 < 6; ++o4) {
        float4 wv = *(float4*)&w_lds[cc * 96 + og * 24 + o4 * 4];
        acc[o4 * 4 + 0] = fmaf(wv.x, a, acc[o4 * 4 + 0]);
        acc[o4 * 4 + 1] = fmaf(wv.y, a, acc[o4 * 4 + 1]);
        acc[o4 * 4 + 2] = fmaf(wv.z, a, acc[o4 * 4 + 2]);
        acc[o4 * 4 + 3] = fmaf(wv.w, a, acc[o4 * 4 + 3]);
      }
    }
  }
  const float* xb = x + (size_t)b * NC * NPT;
  float* ob = out + (size_t)b * NC * NPT;
#pragma unroll
  for (int oo = 0; oo < 24; ++oo) {
    int o = og * 24 + oo;
    ob[(size_t)o * NPT + n] = acc[oo] + b2f[o] + xb[(size_t)o * NPT + n];
  }
}

extern "C" void kernel_launch(void* const* d_in, const int* in_sizes, int n_in,
                              void* d_out, int out_size, void* d_ws, size_t ws_size,
                              hipStream_t stream) {
  const float* x  = (const float*)d_in[0];
  const float* W1 = (const float*)d_in[1];
  const float* b1 = (const float*)d_in[2];
  const float* g1 = (const float*)d_in[3];
  const float* be1= (const float*)d_in[4];
  const float* m1 = (const float*)d_in[5];
  const float* v1 = (const float*)d_in[6];
  const float* Wg = (const float*)d_in[7];
  const float* bg = (const float*)d_in[8];
  const float* W2 = (const float*)d_in[9];
  const float* b2 = (const float*)d_in[10];
  const float* g2 = (const float*)d_in[11];
  const float* be2= (const float*)d_in[12];
  const float* m2 = (const float*)d_in[13];
  const float* v2 = (const float*)d_in[14];
  float* out = (float*)d_out;

  float* ws = (float*)d_ws;
  size_t off = 0;
  float* feat = ws + off; off += (size_t)NB * NC * NPT;
  float* fnp  = ws + off; off += (size_t)NB * NC * NPT;
  float* sqv  = ws + off; off += (size_t)NB * NPT;
  float* uvt  = ws + off; off += (size_t)NB * NPT * 384;   // also hosts pk before k_uv
  float* aggt = ws + off; off += (size_t)NB * NPT * 192;
  float* W1f  = ws + off; off += NC * NC;
  float* Wuv  = ws + off; off += NC * 2 * NC2;
  float* W2f  = ws + off; off += NC2 * NC;
  float* b1f  = ws + off; off += 128;
  float* b2f  = ws + off; off += 128;
  int* nn_idx = (int*)(ws + off); off += (size_t)NB * NPT * NK;

  u64* pk = (u64*)uvt;  // 25088*18 u64 = 3.6 MB << uvt's 38.5 MB; consumed before k_uv

  k_fuse<<<dim3(64), 256, 0, stream>>>(W1, b1, g1, be1, m1, v1, Wg, W2, b2, g2, be2, m2, v2,
                                       W1f, b1f, Wuv, W2f, b2f);
  k_feat<<<dim3((NPT + 255) / 256, NB), 256, 0, stream>>>(x, W1f, b1f, feat, fnp, sqv);
  k_knn<<<dim3(NB * (NPT / 32) * 2), 256, 0, stream>>>(fnp, sqv, pk);
  k_nnmerge<<<dim3((NB * NPT + 255) / 256), 256, 0, stream>>>(pk, nn_idx);
  k_uv<<<dim3(NPT / 64, NB), 256, 0, stream>>>(feat, Wuv, bg, uvt);
  k_gather<<<dim3(NB * NPT), 192, 0, stream>>>(uvt, nn_idx, aggt);
  k_out<<<dim3(NPT / 64, NB), 256, 0, stream>>>(aggt, W2f, b2f, x, out);
}